// Round 9
// baseline (232.974 us; speedup 1.0000x reference)
//
#include <hip/hip_runtime.h>
#include <stdint.h>

#define N_NODES 100000
#define N_EDGES 1000000
#define DIM 64
#define MAXD 32                  // ELL width: 128B index row per node
#define BKT_SHIFT 7
#define BKT_NODES 128            // nodes per bucket
#define NBKT ((N_NODES + BKT_NODES - 1) / BKT_NODES)   // 782
#define BKT_CAP 2048             // >>20 sigma above mean 1279 edges/bucket
#define OVF_CAP 16384
#define CHUNK 8192               // edges per scatter block
#define NCHUNK ((N_EDGES + CHUNK - 1) / CHUNK)         // 123
#define CURS_STRIDE 16           // 64B-padded cursors: one line each
#define LROWS 64                 // linear: rows per block

__device__ __forceinline__ int load_src(const void* edges, int is64, int e) {
    if (is64) return ((const int2*)edges)[e].x;            // int64 values < 2^31
    return ((const int*)edges)[e];
}
__device__ __forceinline__ int load_dst(const void* edges, int is64, int e) {
    if (is64) return ((const int2*)edges)[N_EDGES + e].x;
    return ((const int*)edges)[N_EDGES + e];
}

// zero cnt + padded cursors + ovf_cnt; detect edge dtype (thread 0)
__global__ void init_kernel(const void* __restrict__ edges, int* __restrict__ flag,
                            int* __restrict__ cursors, int* __restrict__ cnt,
                            int* __restrict__ ovf_cnt) {
    int i = blockIdx.x * blockDim.x + threadIdx.x;
    if (i < N_NODES) cnt[i] = 0;
    if (i < NBKT * CURS_STRIDE) cursors[i] = 0;
    if (i == 0) {
        *ovf_cnt = 0;
        const long long* e64 = (const long long*)edges;
        int is64 = 1;
        for (int k = 0; k < 8; ++k) {
            long long v = e64[k];
            if (v < 0 || v >= (long long)N_NODES) is64 = 0;
        }
        *flag = is64;
    }
}

// two-pass per-block radix scatter into dst-range buckets.
__global__ __launch_bounds__(256) void bucket_scatter(const void* __restrict__ edges,
                                                      const int* __restrict__ flag,
                                                      int* __restrict__ cursors,
                                                      int* __restrict__ cnt,
                                                      int* __restrict__ buckets,
                                                      int2* __restrict__ ovf,
                                                      int* __restrict__ ovf_cnt) {
    __shared__ int lcnt[NBKT];
    __shared__ int lbase[NBKT];
    int t = threadIdx.x;
    int e0 = blockIdx.x * CHUNK;
    int e1 = min(e0 + CHUNK, N_EDGES);
    int is64 = *flag;
    for (int i = t; i < NBKT; i += 256) lcnt[i] = 0;
    __syncthreads();
    for (int e = e0 + t; e < e1; e += 256) {           // pass 1: count
        int d = load_dst(edges, is64, e);
        atomicAdd(&lcnt[d >> BKT_SHIFT], 1);
    }
    __syncthreads();
    for (int i = t; i < NBKT; i += 256) {              // reserve ranges
        int c = lcnt[i];
        lbase[i] = c ? atomicAdd(&cursors[i * CURS_STRIDE], c) : 0;
        lcnt[i] = 0;                                   // reuse as local cursor
    }
    __syncthreads();
    for (int e = e0 + t; e < e1; e += 256) {           // pass 2: scatter
        int s = load_src(edges, is64, e);
        int d = load_dst(edges, is64, e);
        int b = d >> BKT_SHIFT;
        int pos = lbase[b] + atomicAdd(&lcnt[b], 1);
        if (pos < BKT_CAP) {
            buckets[(size_t)b * BKT_CAP + pos] = s | ((d & (BKT_NODES - 1)) << 17);
        } else {                                       // astronomically rare
            atomicAdd(&cnt[d], 1);
            int o = atomicAdd(ovf_cnt, 1);
            if (o < OVF_CAP) ovf[o] = make_int2(s, d);
        }
    }
}

// per-bucket ELL build: LDS degree counters; finalizes cnt/ellcnt/dinv.
__global__ __launch_bounds__(256) void ell_build(const int* __restrict__ cursors,
                                                 int* __restrict__ cnt,
                                                 int* __restrict__ ellcnt,
                                                 float* __restrict__ dinv,
                                                 const int* __restrict__ buckets,
                                                 int* __restrict__ ell,
                                                 int2* __restrict__ ovf,
                                                 int* __restrict__ ovf_cnt) {
    __shared__ int lcnt[BKT_NODES];
    int b = blockIdx.x, t = threadIdx.x;
    if (t < BKT_NODES) lcnt[t] = 0;
    __syncthreads();
    int m = cursors[b * CURS_STRIDE];
    if (m > BKT_CAP) m = BKT_CAP;
    int base = b * BKT_NODES;
    const int* be = buckets + (size_t)b * BKT_CAP;
    for (int i = t; i < m; i += 256) {
        int pe = be[i];
        int s = pe & 0x1FFFF;
        int off = pe >> 17;
        int k = atomicAdd(&lcnt[off], 1);
        if (k < MAXD) ell[(size_t)(base + off) * MAXD + k] = s;
        else {
            int o = atomicAdd(ovf_cnt, 1);
            if (o < OVF_CAP) ovf[o] = make_int2(s, base + off);
        }
    }
    __syncthreads();
    if (t < BKT_NODES) {
        int g = base + t;
        if (g < N_NODES) {
            int tot = cnt[g] + lcnt[t];
            cnt[g] = tot;
            ellcnt[g] = lcnt[t] < MAXD ? lcnt[t] : MAXD;
            dinv[g] = rsqrtf((float)(tot + 1));
        }
    }
}

// MODE 0: vin = x, edge weight dinv[s], self term dn*x[n] (fused vinit)
// MODE 1: mid hop in v-space; MODE 2: final hop, scale dn (back to x-space)
template <int MODE>
__global__ __launch_bounds__(256) void hop_kernel(const float* __restrict__ vin,
                                                  const int* __restrict__ ellcnt,
                                                  const int* __restrict__ ell,
                                                  const float* __restrict__ dinv,
                                                  const int2* __restrict__ ovf,
                                                  const int* __restrict__ ovf_cnt,
                                                  float* __restrict__ y) {
    int t = blockIdx.x * blockDim.x + threadIdx.x;
    int n = t >> 6;
    if (n >= N_NODES) return;
    int d = t & 63;
    int deg = ellcnt[n];                       // wave-uniform
    int idx = ell[(n << 5) + (d & 31)];        // 128B coalesced row
    float dn = dinv[n];
    float acc = (MODE == 0) ? dn * vin[n * DIM + d] : vin[n * DIM + d];
    int deg8 = (deg + 7) & ~7;
    for (int j = 0; j < deg8; j += 8) {
#pragma unroll
        for (int kk = 0; kk < 8; ++kk) {
            int jj = j + kk;
            int s = __shfl(idx, jj, 64);       // wave-uniform index
            bool val = jj < deg;
            s = val ? s : 0;                   // masked slots hit hot row 0
            float w;
            if (MODE == 0) { float dv = dinv[s]; w = val ? dv : 0.0f; }
            else           { w = val ? 1.0f : 0.0f; }
            acc = fmaf(w, vin[s * DIM + d], acc);
        }
    }
    int m = *ovf_cnt;                          // expected 0
    if (m > OVF_CAP) m = OVF_CAP;
    for (int i = 0; i < m; ++i) {
        int2 e = ovf[i];
        if (e.y == n) {
            float w = (MODE == 0) ? dinv[e.x] : 1.0f;
            acc = fmaf(w, vin[e.x * DIM + d], acc);
        }
    }
    float scale = (MODE == 2) ? dn : dn * dn;
    y[n * DIM + d] = scale * acc;
}

// out = x @ W^T. 64x64 tile, 4x4 per thread, dot-product form.
// x staged row-major in LDS (contiguous float4 writes, conflict-free);
// W read as float4 from global (16KB, L1-hot across blocks). k-loop
// unrolled x2 only, keeping live set ~64 regs -> high occupancy.
__global__ __launch_bounds__(256) void linear_kernel(const float* __restrict__ x,
                                                     const float* __restrict__ W,
                                                     float* __restrict__ out) {
    __shared__ float sx[LROWS][DIM];   // 16 KB
    int tid = threadIdx.x;
    size_t row0 = (size_t)blockIdx.x * LROWS;

    // stage x tile row-major: each 16-lane group writes a contiguous 256B run
    for (int it = 0; it < 4; ++it) {
        int i = tid + it * 256;                 // float4 slot in 64x64 tile
        int r = i >> 4;
        int k4 = (i & 15) * 4;
        size_t gr = row0 + r;
        if (gr >= N_NODES) gr = N_NODES - 1;    // clamp (masked at store)
        *(float4*)&sx[r][k4] = *(const float4*)&x[gr * DIM + k4];
    }
    __syncthreads();

    int r0 = (tid >> 4) * 4;
    int c0 = (tid & 15) * 4;
    float acc[4][4] = {{0.f}};
#pragma unroll 2
    for (int k = 0; k < DIM; k += 4) {
        float4 xa[4], wa[4];
#pragma unroll
        for (int i = 0; i < 4; ++i) xa[i] = *(const float4*)&sx[r0 + i][k];
#pragma unroll
        for (int j = 0; j < 4; ++j) wa[j] = *(const float4*)&W[(size_t)(c0 + j) * DIM + k];
#pragma unroll
        for (int i = 0; i < 4; ++i)
#pragma unroll
            for (int j = 0; j < 4; ++j)
                acc[i][j] += xa[i].x * wa[j].x + xa[i].y * wa[j].y
                           + xa[i].z * wa[j].z + xa[i].w * wa[j].w;
    }
#pragma unroll
    for (int i = 0; i < 4; ++i) {
        size_t gr = row0 + r0 + i;
        if (gr < N_NODES) {
            float4 o = make_float4(acc[i][0], acc[i][1], acc[i][2], acc[i][3]);
            *(float4*)&out[gr * DIM + c0] = o;
        }
    }
}

extern "C" void kernel_launch(void* const* d_in, const int* in_sizes, int n_in,
                              void* d_out, int out_size, void* d_ws, size_t ws_size,
                              hipStream_t stream) {
    const float* x     = (const float*)d_in[0];
    const float* W     = (const float*)d_in[1];
    const void*  edges = d_in[2];
    float* out = (float*)d_out;

    char* ws = (char*)d_ws;
    int*   flag    = (int*)(ws + 0);
    int*   ovf_cnt = (int*)(ws + 4);
    int*   cursors = (int*)(ws + 4096);        // 782*16 ints, line-padded
    int*   cnt     = (int*)(ws + 65536);       // 400 KB
    int*   ellcnt  = (int*)(ws + 465536);      // 400 KB
    float* dinv    = (float*)(ws + 865536);    // 400 KB
    int2*  ovf     = (int2*)(ws + 1265536);    // 128 KB
    int*   ell     = (int*)(ws + 1396608);     // 12.8 MB
    float* bufA    = (float*)(ws + 14196608);  // 25.6 MB
    float* bufB    = (float*)(ws + 39796864);  // 25.6 MB
    // buckets (6.4 MB, packed ints) aliased into bufB tail: dead before hop<1>
    int*   buckets = (int*)(ws + 58990976);

    const int NB = (N_NODES + 255) / 256;
    const int HB = (N_NODES * 64 + 255) / 256;
    const int LB = (N_NODES + LROWS - 1) / LROWS;

    init_kernel<<<NB, 256, 0, stream>>>(edges, flag, cursors, cnt, ovf_cnt);
    bucket_scatter<<<NCHUNK, 256, 0, stream>>>(edges, flag, cursors, cnt, buckets, ovf, ovf_cnt);
    ell_build<<<NBKT, 256, 0, stream>>>(cursors, cnt, ellcnt, dinv, buckets, ell, ovf, ovf_cnt);

    // hop1 (reads x directly): x -> bufA ; hop2: bufA -> bufB ; hop3: bufB -> bufA
    hop_kernel<0><<<HB, 256, 0, stream>>>(x,    ellcnt, ell, dinv, ovf, ovf_cnt, bufA);
    hop_kernel<1><<<HB, 256, 0, stream>>>(bufA, ellcnt, ell, dinv, ovf, ovf_cnt, bufB);
    hop_kernel<2><<<HB, 256, 0, stream>>>(bufB, ellcnt, ell, dinv, ovf, ovf_cnt, bufA);

    linear_kernel<<<LB, 256, 0, stream>>>(bufA, W, out);
}

// Round 10
// 215.035 us; speedup vs baseline: 1.0834x; 1.0834x over previous
//
#include <hip/hip_runtime.h>
#include <stdint.h>

#define N_NODES 100000
#define N_EDGES 1000000
#define DIM 64
#define MAXD 32                  // ELL width: 128B index row per node
#define BKT_SHIFT 7
#define BKT_NODES 128            // nodes per bucket
#define NBKT ((N_NODES + BKT_NODES - 1) / BKT_NODES)   // 782
#define BKT_CAP 2048             // >>20 sigma above mean 1279 edges/bucket
#define OVF_CAP 16384
#define CHUNK 8192               // edges per scatter block
#define NCHUNK ((N_EDGES + CHUNK - 1) / CHUNK)         // 123
#define CURS_STRIDE 16           // 64B-padded cursors: one line each

__device__ __forceinline__ int load_src(const void* edges, int is64, int e) {
    if (is64) return ((const int2*)edges)[e].x;            // int64 values < 2^31
    return ((const int*)edges)[e];
}
__device__ __forceinline__ int load_dst(const void* edges, int is64, int e) {
    if (is64) return ((const int2*)edges)[N_EDGES + e].x;
    return ((const int*)edges)[N_EDGES + e];
}

// zero cnt + padded cursors + ovf_cnt; detect edge dtype (thread 0)
__global__ void init_kernel(const void* __restrict__ edges, int* __restrict__ flag,
                            int* __restrict__ cursors, int* __restrict__ cnt,
                            int* __restrict__ ovf_cnt) {
    int i = blockIdx.x * blockDim.x + threadIdx.x;
    if (i < N_NODES) cnt[i] = 0;
    if (i < NBKT * CURS_STRIDE) cursors[i] = 0;
    if (i == 0) {
        *ovf_cnt = 0;
        const long long* e64 = (const long long*)edges;
        int is64 = 1;
        for (int k = 0; k < 8; ++k) {
            long long v = e64[k];
            if (v < 0 || v >= (long long)N_NODES) is64 = 0;
        }
        *flag = is64;
    }
}

// two-pass per-block radix scatter into dst-range buckets.
__global__ __launch_bounds__(256) void bucket_scatter(const void* __restrict__ edges,
                                                      const int* __restrict__ flag,
                                                      int* __restrict__ cursors,
                                                      int* __restrict__ cnt,
                                                      int* __restrict__ buckets,
                                                      int2* __restrict__ ovf,
                                                      int* __restrict__ ovf_cnt) {
    __shared__ int lcnt[NBKT];
    __shared__ int lbase[NBKT];
    int t = threadIdx.x;
    int e0 = blockIdx.x * CHUNK;
    int e1 = min(e0 + CHUNK, N_EDGES);
    int is64 = *flag;
    for (int i = t; i < NBKT; i += 256) lcnt[i] = 0;
    __syncthreads();
    for (int e = e0 + t; e < e1; e += 256) {           // pass 1: count
        int d = load_dst(edges, is64, e);
        atomicAdd(&lcnt[d >> BKT_SHIFT], 1);
    }
    __syncthreads();
    for (int i = t; i < NBKT; i += 256) {              // reserve ranges
        int c = lcnt[i];
        lbase[i] = c ? atomicAdd(&cursors[i * CURS_STRIDE], c) : 0;
        lcnt[i] = 0;                                   // reuse as local cursor
    }
    __syncthreads();
    for (int e = e0 + t; e < e1; e += 256) {           // pass 2: scatter
        int s = load_src(edges, is64, e);
        int d = load_dst(edges, is64, e);
        int b = d >> BKT_SHIFT;
        int pos = lbase[b] + atomicAdd(&lcnt[b], 1);
        if (pos < BKT_CAP) {
            buckets[(size_t)b * BKT_CAP + pos] = s | ((d & (BKT_NODES - 1)) << 17);
        } else {                                       // astronomically rare
            atomicAdd(&cnt[d], 1);
            int o = atomicAdd(ovf_cnt, 1);
            if (o < OVF_CAP) ovf[o] = make_int2(s, d);
        }
    }
}

// per-bucket ELL build: LDS degree counters; finalizes cnt/ellcnt/dinv.
__global__ __launch_bounds__(256) void ell_build(const int* __restrict__ cursors,
                                                 int* __restrict__ cnt,
                                                 int* __restrict__ ellcnt,
                                                 float* __restrict__ dinv,
                                                 const int* __restrict__ buckets,
                                                 int* __restrict__ ell,
                                                 int2* __restrict__ ovf,
                                                 int* __restrict__ ovf_cnt) {
    __shared__ int lcnt[BKT_NODES];
    int b = blockIdx.x, t = threadIdx.x;
    if (t < BKT_NODES) lcnt[t] = 0;
    __syncthreads();
    int m = cursors[b * CURS_STRIDE];
    if (m > BKT_CAP) m = BKT_CAP;
    int base = b * BKT_NODES;
    const int* be = buckets + (size_t)b * BKT_CAP;
    for (int i = t; i < m; i += 256) {
        int pe = be[i];
        int s = pe & 0x1FFFF;
        int off = pe >> 17;
        int k = atomicAdd(&lcnt[off], 1);
        if (k < MAXD) ell[(size_t)(base + off) * MAXD + k] = s;
        else {
            int o = atomicAdd(ovf_cnt, 1);
            if (o < OVF_CAP) ovf[o] = make_int2(s, base + off);
        }
    }
    __syncthreads();
    if (t < BKT_NODES) {
        int g = base + t;
        if (g < N_NODES) {
            int tot = cnt[g] + lcnt[t];
            cnt[g] = tot;
            ellcnt[g] = lcnt[t] < MAXD ? lcnt[t] : MAXD;
            dinv[g] = rsqrtf((float)(tot + 1));
        }
    }
}

// MODE 0: vin = x, edge weight dinv[s], self term dn*x[n] (fused vinit)
// MODE 1: mid hop in v-space; MODE 2: final hop, scale dn (back to x-space)
template <int MODE>
__global__ __launch_bounds__(256) void hop_kernel(const float* __restrict__ vin,
                                                  const int* __restrict__ ellcnt,
                                                  const int* __restrict__ ell,
                                                  const float* __restrict__ dinv,
                                                  const int2* __restrict__ ovf,
                                                  const int* __restrict__ ovf_cnt,
                                                  float* __restrict__ y) {
    int t = blockIdx.x * blockDim.x + threadIdx.x;
    int n = t >> 6;
    if (n >= N_NODES) return;
    int d = t & 63;
    int deg = ellcnt[n];                       // wave-uniform
    int idx = ell[(n << 5) + (d & 31)];        // 128B coalesced row
    float dn = dinv[n];
    float acc = (MODE == 0) ? dn * vin[n * DIM + d] : vin[n * DIM + d];
    int deg8 = (deg + 7) & ~7;
    for (int j = 0; j < deg8; j += 8) {
#pragma unroll
        for (int kk = 0; kk < 8; ++kk) {
            int jj = j + kk;
            int s = __shfl(idx, jj, 64);       // wave-uniform index
            bool val = jj < deg;
            s = val ? s : 0;                   // masked slots hit hot row 0
            float w;
            if (MODE == 0) { float dv = dinv[s]; w = val ? dv : 0.0f; }
            else           { w = val ? 1.0f : 0.0f; }
            acc = fmaf(w, vin[s * DIM + d], acc);
        }
    }
    int m = *ovf_cnt;                          // expected 0
    if (m > OVF_CAP) m = OVF_CAP;
    for (int i = 0; i < m; ++i) {
        int2 e = ovf[i];
        if (e.y == n) {
            float w = (MODE == 0) ? dinv[e.x] : 1.0f;
            acc = fmaf(w, vin[e.x * DIM + d], acc);
        }
    }
    float scale = (MODE == 2) ? dn : dn * dn;
    y[n * DIM + d] = scale * acc;
}

// out = x @ W^T. Row-per-lane: lane r owns out[row0+r,:]; x row in 16 float4
// VGPRs (loaded once, fully-unrolled static indexing); W[c][k] is wave-uniform
// -> scalar-cache s_loads on the scalar pipe, parallel to VALU. 4 independent
// FMA chains (c0..c0+3) hide the 4cy FMA latency. No LDS.
__global__ __launch_bounds__(64) void linear_kernel(const float* __restrict__ x,
                                                    const float* __restrict__ W,
                                                    float* __restrict__ out) {
    int lane = threadIdx.x;                    // 0..63
    size_t row = (size_t)blockIdx.x * 64 + lane;
    bool valid = row < N_NODES;
    if (!valid) row = N_NODES - 1;             // clamp loads; mask store
    float4 xr[16];
    const float4* xv = (const float4*)(x + row * DIM);
#pragma unroll
    for (int q = 0; q < 16; ++q) xr[q] = xv[q];
    for (int c0 = 0; c0 < DIM; c0 += 4) {
        const float* w0 = W + (size_t)(c0 + 0) * DIM;
        const float* w1 = W + (size_t)(c0 + 1) * DIM;
        const float* w2 = W + (size_t)(c0 + 2) * DIM;
        const float* w3 = W + (size_t)(c0 + 3) * DIM;
        float a0 = 0.f, a1 = 0.f, a2 = 0.f, a3 = 0.f;
#pragma unroll
        for (int q = 0; q < 16; ++q) {
            float xk[4] = {xr[q].x, xr[q].y, xr[q].z, xr[q].w};
#pragma unroll
            for (int u = 0; u < 4; ++u) {
                int k = q * 4 + u;
                a0 = fmaf(xk[u], w0[k], a0);   // v_fmac v, s, v
                a1 = fmaf(xk[u], w1[k], a1);
                a2 = fmaf(xk[u], w2[k], a2);
                a3 = fmaf(xk[u], w3[k], a3);
            }
        }
        if (valid) *(float4*)&out[row * DIM + c0] = make_float4(a0, a1, a2, a3);
    }
}

extern "C" void kernel_launch(void* const* d_in, const int* in_sizes, int n_in,
                              void* d_out, int out_size, void* d_ws, size_t ws_size,
                              hipStream_t stream) {
    const float* x     = (const float*)d_in[0];
    const float* W     = (const float*)d_in[1];
    const void*  edges = d_in[2];
    float* out = (float*)d_out;

    char* ws = (char*)d_ws;
    int*   flag    = (int*)(ws + 0);
    int*   ovf_cnt = (int*)(ws + 4);
    int*   cursors = (int*)(ws + 4096);        // 782*16 ints, line-padded
    int*   cnt     = (int*)(ws + 65536);       // 400 KB
    int*   ellcnt  = (int*)(ws + 465536);      // 400 KB
    float* dinv    = (float*)(ws + 865536);    // 400 KB
    int2*  ovf     = (int2*)(ws + 1265536);    // 128 KB
    int*   ell     = (int*)(ws + 1396608);     // 12.8 MB
    float* bufA    = (float*)(ws + 14196608);  // 25.6 MB
    float* bufB    = (float*)(ws + 39796864);  // 25.6 MB
    // buckets (6.4 MB, packed ints) aliased into bufB tail: dead before hop<1>
    int*   buckets = (int*)(ws + 58990976);

    const int NB = (N_NODES + 255) / 256;
    const int HB = (N_NODES * 64 + 255) / 256;
    const int LB = (N_NODES + 63) / 64;

    init_kernel<<<NB, 256, 0, stream>>>(edges, flag, cursors, cnt, ovf_cnt);
    bucket_scatter<<<NCHUNK, 256, 0, stream>>>(edges, flag, cursors, cnt, buckets, ovf, ovf_cnt);
    ell_build<<<NBKT, 256, 0, stream>>>(cursors, cnt, ellcnt, dinv, buckets, ell, ovf, ovf_cnt);

    // hop1 (reads x directly): x -> bufA ; hop2: bufA -> bufB ; hop3: bufB -> bufA
    hop_kernel<0><<<HB, 256, 0, stream>>>(x,    ellcnt, ell, dinv, ovf, ovf_cnt, bufA);
    hop_kernel<1><<<HB, 256, 0, stream>>>(bufA, ellcnt, ell, dinv, ovf, ovf_cnt, bufB);
    hop_kernel<2><<<HB, 256, 0, stream>>>(bufB, ellcnt, ell, dinv, ovf, ovf_cnt, bufA);

    linear_kernel<<<LB, 64, 0, stream>>>(bufA, W, out);
}